// Round 6
// baseline (246.142 us; speedup 1.0000x reference)
//
#include <hip/hip_runtime.h>

// GAT (heads=1) + mean-pool + FC, specialized.
//   pooled[f] = (1/N) * sum_n c[n]*h[n][f] + b_gat[f]
//   c[n] = sum_{edges e: src=n} ex_e * rden[dst_e]
//   rden[d] = 1 / (sum_{edges e: dst=d} ex_e + ex_self_d + 1e-16)
// Device-scope scattered atomics cap at ~19 G/s (1/cyc/XCD), so both scatter
// passes are multi-range LDS histograms (ds_add_f32) + non-atomic slab flush +
// coalesced reduce. Self loops folded analytically into the reduce kernels.
// RSZ=4864 (19KB LDS) * 256thr -> 8 blk/CU * 4 waves = 32 waves/CU (wave cap)
// to hide the masked-gather latency chain. Pass 1 stores per-edge ex (each
// edge's dst in exactly one range -> written exactly once); pass 2 then only
// gathers rden[d]. h is never materialized: k_pool recomputes h from x via
// wave-uniform scalar loads (W rows in 5 VGPRs).
// Range-blocks of one chunk share blockIdx%8 -> same XCD -> chunk re-reads
// hit local L2 (perf heuristic only).
// segment_max skipped: alpha invariant to max-shift; |e| is O(10) -> exp safe.

#define NRANGE 21
#define RSZ 4864        // 21*4864 = 102144 >= N ; 19,456 B LDS
#define HTHREADS 256
#define G_CHUNKS 96     // multiple of 8; grid = 21*96 = 2016
#define POOL_BLOCKS 512

// ---- kernel 1: a_s = (x@W).att_src ; a_d = (x@W).att_dst (h not stored) ----
__global__ __launch_bounds__(256) void k_att(
    const float* __restrict__ x, const float* __restrict__ W,
    const float* __restrict__ att_src, const float* __restrict__ att_dst,
    float* __restrict__ a_s, float* __restrict__ a_d, int N) {
  const int lane = threadIdx.x & 63;
  const int n = blockIdx.x * 4 + (threadIdx.x >> 6);
  if (n >= N) return;
  const float x0 = x[n * 5 + 0], x1 = x[n * 5 + 1], x2 = x[n * 5 + 2],
              x3 = x[n * 5 + 3], x4 = x[n * 5 + 4];
  float hv = x0 * W[0 * 64 + lane];
  hv += x1 * W[1 * 64 + lane];
  hv += x2 * W[2 * 64 + lane];
  hv += x3 * W[3 * 64 + lane];
  hv += x4 * W[4 * 64 + lane];
  float t1 = hv * att_src[lane];
  float t2 = hv * att_dst[lane];
#pragma unroll
  for (int o = 32; o > 0; o >>= 1) {
    t1 += __shfl_xor(t1, o, 64);
    t2 += __shfl_xor(t2, o, 64);
  }
  if (lane == 0) {
    a_s[n] = t1;
    a_d[n] = t2;
  }
}

// ---- histogram pass; PASS=1: key=dst, val=ex (also stores ex[j]);
//      PASS=2: key=src, val=ex[j]*rden[dst]. ----
template <int PASS>
__global__ __launch_bounds__(HTHREADS) void k_hist(
    const int* __restrict__ ei, const float* __restrict__ a_s,
    const float* __restrict__ a_d, const float* __restrict__ rden,
    float* __restrict__ exbuf, float* __restrict__ slab, int E) {
  __shared__ float hist[RSZ];
  const int b = blockIdx.x;
  const int xx = b & 7;
  const int q = b >> 3;
  const int r = q % NRANGE;                 // range id
  const int bg = (q / NRANGE) * 8 + xx;     // chunk id (same xcd per chunk)
  const int base = r * RSZ;
  for (int i = threadIdx.x; i < RSZ; i += HTHREADS) hist[i] = 0.f;
  __syncthreads();
  const int chunk = (E + G_CHUNKS - 1) / G_CHUNKS;
  const int lo = bg * chunk;
  const int hi = (lo + chunk < E) ? lo + chunk : E;
#pragma unroll 4
  for (int j = lo + threadIdx.x; j < hi; j += HTHREADS) {
    if (PASS == 1) {
      const int d = ei[E + j];
      const unsigned ki = (unsigned)(d - base);
      if (ki < (unsigned)RSZ) {
        const int s = ei[j];
        float e = a_s[s] + a_d[d];
        e = e > 0.f ? e : 0.2f * e;
        const float v = __expf(e);
        exbuf[j] = v;
        atomicAdd(&hist[ki], v);
      }
    } else {
      const int s = ei[j];
      const unsigned ki = (unsigned)(s - base);
      if (ki < (unsigned)RSZ) {
        const int d = ei[E + j];
        const float v = exbuf[j] * rden[d];
        atomicAdd(&hist[ki], v);
      }
    }
  }
  __syncthreads();
  float* outp = slab + ((size_t)r * G_CHUNKS + bg) * RSZ;
  for (int i = threadIdx.x; i < RSZ; i += HTHREADS) outp[i] = hist[i];
}

// ---- reduce slabs; PASS=1 -> rden[n] = 1/(sum+ex_self+eps);
//      PASS=2 -> c[n] = sum + ex_self*rden[n] ----
template <int PASS>
__global__ __launch_bounds__(256) void k_red(
    const float* __restrict__ slab, const float* __restrict__ a_s,
    const float* __restrict__ a_d, const float* __restrict__ rden_in,
    float* __restrict__ outarr, int N) {
  const int n = blockIdx.x * 256 + threadIdx.x;
  if (n >= N) return;
  const int g = n / RSZ;
  const int i = n - g * RSZ;
  const float* sp = slab + ((size_t)g * G_CHUNKS) * RSZ + i;
  float sum = 0.f;
#pragma unroll 8
  for (int bg = 0; bg < G_CHUNKS; ++bg) sum += sp[(size_t)bg * RSZ];
  float e = a_s[n] + a_d[n];
  e = e > 0.f ? e : 0.2f * e;
  const float ex_self = __expf(e);
  if (PASS == 1)
    outarr[n] = 1.0f / (sum + ex_self + 1e-16f);
  else
    outarr[n] = sum + ex_self * rden_in[n];
}

// ---- pooled partials: partial[blk][f] = sum_chunk c[n]*h[n][f],
//      h recomputed from x (wave-uniform scalar loads) ----
__global__ __launch_bounds__(256) void k_pool(
    const float* __restrict__ x, const float* __restrict__ W,
    const float* __restrict__ c, float* __restrict__ partial, int N) {
  const int lane = threadIdx.x & 63;
  const int lw = threadIdx.x >> 6;
  const int wid = blockIdx.x * 4 + lw;
  const int nw = gridDim.x * 4;
  const float w0 = W[0 * 64 + lane], w1 = W[1 * 64 + lane],
              w2 = W[2 * 64 + lane], w3 = W[3 * 64 + lane],
              w4 = W[4 * 64 + lane];
  const int nchunk = (N + 63) / 64;
  float acc = 0.f;
  for (int ch = wid; ch < nchunk; ch += nw) {
    const int base = ch * 64;
    const int nl = base + lane;
    const float cv = (nl < N) ? c[nl] : 0.f;
#pragma unroll 8
    for (int k = 0; k < 64; ++k) {
      const float ck = __shfl(cv, k, 64);
      int nn = base + k;
      nn = nn < N ? nn : N - 1;  // clamp (weight is 0 for OOB lanes)
      const float* xp = x + (size_t)nn * 5;  // wave-uniform -> s_load
      const float hv =
          xp[0] * w0 + xp[1] * w1 + xp[2] * w2 + xp[3] * w3 + xp[4] * w4;
      acc += ck * hv;
    }
  }
  __shared__ float sacc[4][64];
  sacc[lw][lane] = acc;
  __syncthreads();
  if (threadIdx.x < 64) {
    partial[blockIdx.x * 64 + lane] =
        sacc[0][lane] + sacc[1][lane] + sacc[2][lane] + sacc[3][lane];
  }
}

// ---- reduce partials, /N + b_gat, FC 64->72 + relu ----
__global__ __launch_bounds__(256) void k_finish(
    const float* __restrict__ partial, int nparts,
    const float* __restrict__ b_gat, const float* __restrict__ W_fc,
    const float* __restrict__ b_fc, float* __restrict__ out, float invN) {
  const int lane = threadIdx.x & 63;
  const int lw = threadIdx.x >> 6;
  float acc = 0.f;
  for (int b = lw; b < nparts; b += 4) acc += partial[b * 64 + lane];
  __shared__ float sacc[4][64];
  __shared__ float pooled[64];
  sacc[lw][lane] = acc;
  __syncthreads();
  if (threadIdx.x < 64) {
    pooled[threadIdx.x] =
        (sacc[0][threadIdx.x] + sacc[1][threadIdx.x] + sacc[2][threadIdx.x] +
         sacc[3][threadIdx.x]) *
            invN +
        b_gat[threadIdx.x];
  }
  __syncthreads();
  if (threadIdx.x < 72) {
    float s = b_fc[threadIdx.x];
#pragma unroll
    for (int f = 0; f < 64; ++f) s += pooled[f] * W_fc[f * 72 + threadIdx.x];
    out[threadIdx.x] = s > 0.f ? s : 0.f;
  }
}

extern "C" void kernel_launch(void* const* d_in, const int* in_sizes, int n_in,
                              void* d_out, int out_size, void* d_ws,
                              size_t ws_size, hipStream_t stream) {
  const float* x = (const float*)d_in[0];
  const int* ei = (const int*)d_in[1];
  const float* W = (const float*)d_in[2];
  const float* att_src = (const float*)d_in[3];
  const float* att_dst = (const float*)d_in[4];
  const float* b_gat = (const float*)d_in[5];
  const float* W_fc = (const float*)d_in[6];
  const float* b_fc = (const float*)d_in[7];
  float* out = (float*)d_out;

  const int N = in_sizes[0] / 5;  // 100000
  const int E = in_sizes[1] / 2;  // 1600000

  char* p = (char*)d_ws;
  auto alloc = [&](size_t nbytes) -> void* {
    void* r = (void*)p;
    p += (nbytes + 255) & ~(size_t)255;
    return r;
  };
  float* a_s = (float*)alloc((size_t)N * sizeof(float));
  float* a_d = (float*)alloc((size_t)N * sizeof(float));
  float* rden = (float*)alloc((size_t)N * sizeof(float));
  float* c = (float*)alloc((size_t)N * sizeof(float));
  float* exbuf = (float*)alloc((size_t)E * sizeof(float));
  float* partial = (float*)alloc((size_t)POOL_BLOCKS * 64 * sizeof(float));
  float* slab =
      (float*)alloc((size_t)NRANGE * G_CHUNKS * RSZ * sizeof(float));  // 39 MB

  k_att<<<(N + 3) / 4, 256, 0, stream>>>(x, W, att_src, att_dst, a_s, a_d, N);
  k_hist<1><<<NRANGE * G_CHUNKS, HTHREADS, 0, stream>>>(ei, a_s, a_d, nullptr,
                                                        exbuf, slab, E);
  k_red<1><<<(N + 255) / 256, 256, 0, stream>>>(slab, a_s, a_d, nullptr, rden,
                                                N);
  k_hist<2><<<NRANGE * G_CHUNKS, HTHREADS, 0, stream>>>(ei, a_s, a_d, rden,
                                                        exbuf, slab, E);
  k_red<2><<<(N + 255) / 256, 256, 0, stream>>>(slab, a_s, a_d, rden, c, N);
  k_pool<<<POOL_BLOCKS, 256, 0, stream>>>(x, W, c, partial, N);
  k_finish<<<1, 256, 0, stream>>>(partial, POOL_BLOCKS, b_gat, W_fc, b_fc, out,
                                  1.0f / (float)N);
}

// Round 9
// 167.524 us; speedup vs baseline: 1.4693x; 1.4693x over previous
//
#include <hip/hip_runtime.h>

// GAT (heads=1) + mean-pool + FC, specialized.
//   pooled[f] = (1/N) * sum_n c[n]*h[n][f] + b_gat[f],  h = x@W
//             = (1/N) * sum_k (sum_n c[n]*x[n][k]) * W[k][f]   <- 5-vector!
//   c[n] = sum_{edges e: src=n} ex_e * rden[dst_e]
//   rden[d] = 1 / (sum_{edges e: dst=d} ex_e + ex_self_d + 1e-16)
// Device-scope scattered atomics cap at ~19 G/s, and multi-range LDS
// histograms with R-fold re-scanning cost R*E edge touches. So: bin edges
// ONCE by dst-range and src-range (exact counting sort: count -> scan ->
// scatter with reserved slots), then each hist block reads only its own
// range's contiguous records. Self loops folded analytically into k_red.
// segment_max skipped: alpha invariant to max-shift; |e| is O(10).

#define NR 25           // ranges
#define RSHIFT 12
#define RSZ 4096        // NR*RSZ = 102400 >= N ; 16 KB LDS per hist block
#define RMASK 4095
#define BBIN 256        // binning blocks
#define BINTHR 1024
#define T 8             // hist blocks per range
#define POOLX_BLOCKS 32

// ---- a_s = (x@W).att_src ; a_d = (x@W).att_dst (h never stored) ----
__global__ __launch_bounds__(256) void k_att(
    const float* __restrict__ x, const float* __restrict__ W,
    const float* __restrict__ att_src, const float* __restrict__ att_dst,
    float* __restrict__ a_s, float* __restrict__ a_d, int N) {
  const int lane = threadIdx.x & 63;
  const int n = blockIdx.x * 4 + (threadIdx.x >> 6);
  if (n >= N) return;
  const float x0 = x[n * 5 + 0], x1 = x[n * 5 + 1], x2 = x[n * 5 + 2],
              x3 = x[n * 5 + 3], x4 = x[n * 5 + 4];
  float hv = x0 * W[0 * 64 + lane];
  hv += x1 * W[1 * 64 + lane];
  hv += x2 * W[2 * 64 + lane];
  hv += x3 * W[3 * 64 + lane];
  hv += x4 * W[4 * 64 + lane];
  float t1 = hv * att_src[lane];
  float t2 = hv * att_dst[lane];
#pragma unroll
  for (int o = 32; o > 0; o >>= 1) {
    t1 += __shfl_xor(t1, o, 64);
    t2 += __shfl_xor(t2, o, 64);
  }
  if (lane == 0) {
    a_s[n] = t1;
    a_d[n] = t2;
  }
}

// ---- count per-(range, block) for both binnings ----
__global__ __launch_bounds__(BINTHR) void k_count(
    const int* __restrict__ ei, int* __restrict__ counts_d,
    int* __restrict__ counts_s, int E) {
  __shared__ int cd[NR], cs[NR];
  if (threadIdx.x < NR) {
    cd[threadIdx.x] = 0;
    cs[threadIdx.x] = 0;
  }
  __syncthreads();
  const int chunk = (E + BBIN - 1) / BBIN;
  const int lo = blockIdx.x * chunk;
  const int hi = (lo + chunk < E) ? lo + chunk : E;
#pragma unroll 4
  for (int j = lo + threadIdx.x; j < hi; j += BINTHR) {
    atomicAdd(&cs[ei[j] >> RSHIFT], 1);
    atomicAdd(&cd[ei[E + j] >> RSHIFT], 1);
  }
  __syncthreads();
  if (threadIdx.x < NR) {
    counts_d[threadIdx.x * BBIN + blockIdx.x] = cd[threadIdx.x];
    counts_s[threadIdx.x * BBIN + blockIdx.x] = cs[threadIdx.x];
  }
}

// ---- exact exclusive offsets for both binnings; rinfo = [base_d|tot_d|base_s|tot_s] ----
__global__ __launch_bounds__(BINTHR) void k_scan(
    const int* __restrict__ counts_d, const int* __restrict__ counts_s,
    int* __restrict__ offs_d, int* __restrict__ offs_s,
    int* __restrict__ rinfo) {
  __shared__ int lc[2 * NR * BBIN];  // 51.2 KB
  __shared__ int tot[2 * NR];
  __shared__ int base[2 * NR];
  for (int i = threadIdx.x; i < 2 * NR * BBIN; i += BINTHR)
    lc[i] = (i < NR * BBIN) ? counts_d[i] : counts_s[i - NR * BBIN];
  __syncthreads();
  if (threadIdx.x < 2 * NR) {
    int s = 0;
    const int* row = &lc[threadIdx.x * BBIN];
    for (int b = 0; b < BBIN; ++b) s += row[b];
    tot[threadIdx.x] = s;
  }
  __syncthreads();
  if (threadIdx.x == 0) {
    int a = 0;
    for (int r = 0; r < NR; ++r) {
      base[r] = a;
      a += tot[r];
    }
    a = 0;
    for (int r = 0; r < NR; ++r) {
      base[NR + r] = a;
      a += tot[NR + r];
    }
  }
  __syncthreads();
  if (threadIdx.x < 2 * NR) {
    int run = base[threadIdx.x];
    int* orow = (threadIdx.x < NR) ? &offs_d[threadIdx.x * BBIN]
                                   : &offs_s[(threadIdx.x - NR) * BBIN];
    const int* row = &lc[threadIdx.x * BBIN];
    for (int b = 0; b < BBIN; ++b) {
      orow[b] = run;
      run += row[b];
    }
  }
  if (threadIdx.x < NR) {
    rinfo[0 * NR + threadIdx.x] = base[threadIdx.x];
    rinfo[1 * NR + threadIdx.x] = tot[threadIdx.x];
    rinfo[2 * NR + threadIdx.x] = base[NR + threadIdx.x];
    rinfo[3 * NR + threadIdx.x] = tot[NR + threadIdx.x];
  }
}

// ---- scatter: compute ex once; append (ki_dst, ex) and (ki_src|d<<12, ex) ----
__global__ __launch_bounds__(BINTHR) void k_scatter(
    const int* __restrict__ ei, const float* __restrict__ a_s,
    const float* __restrict__ a_d, const int* __restrict__ offs_d,
    const int* __restrict__ offs_s, uint2* __restrict__ rec_d,
    uint2* __restrict__ rec_s, int E) {
  __shared__ int curd[NR], curs[NR];
  if (threadIdx.x < NR) {
    curd[threadIdx.x] = offs_d[threadIdx.x * BBIN + blockIdx.x];
    curs[threadIdx.x] = offs_s[threadIdx.x * BBIN + blockIdx.x];
  }
  __syncthreads();
  const int chunk = (E + BBIN - 1) / BBIN;
  const int lo = blockIdx.x * chunk;
  const int hi = (lo + chunk < E) ? lo + chunk : E;
#pragma unroll 2
  for (int j = lo + threadIdx.x; j < hi; j += BINTHR) {
    const int s = ei[j];
    const int d = ei[E + j];
    float e = a_s[s] + a_d[d];
    e = e > 0.f ? e : 0.2f * e;
    const float ex = __expf(e);
    const int sd = atomicAdd(&curd[d >> RSHIFT], 1);
    rec_d[sd] = make_uint2((unsigned)(d & RMASK), __float_as_uint(ex));
    const int ss = atomicAdd(&curs[s >> RSHIFT], 1);
    rec_s[ss] = make_uint2((unsigned)(s & RMASK) | ((unsigned)d << RSHIFT),
                           __float_as_uint(ex));
  }
}

// ---- histogram over binned records; PASS=1: dst/ex ; PASS=2: src/ex*rden[d] ----
template <int PASS>
__global__ __launch_bounds__(256) void k_hist(
    const uint2* __restrict__ rec, const int* __restrict__ rinfo,
    const float* __restrict__ rden, float* __restrict__ slab) {
  __shared__ float hist[RSZ];
  const int r = blockIdx.x / T;
  const int t = blockIdx.x % T;
  for (int i = threadIdx.x; i < RSZ; i += 256) hist[i] = 0.f;
  __syncthreads();
  const int base = rinfo[(PASS == 1 ? 0 : 2) * NR + r];
  const int tot = rinfo[(PASS == 1 ? 1 : 3) * NR + r];
  const int L = (tot + T - 1) / T;
  const int lo = base + t * L;
  const int hh = (t + 1) * L < tot ? (t + 1) * L : tot;
  const int hi = base + hh;
#pragma unroll 4
  for (int j = lo + threadIdx.x; j < hi; j += 256) {
    const uint2 rv = rec[j];
    float v = __uint_as_float(rv.y);
    unsigned ki;
    if (PASS == 1) {
      ki = rv.x;
    } else {
      ki = rv.x & RMASK;
      v *= rden[rv.x >> RSHIFT];
    }
    atomicAdd(&hist[ki], v);
  }
  __syncthreads();
  float* outp = slab + ((size_t)(r * T + t)) * RSZ;
  for (int i = threadIdx.x; i < RSZ; i += 256) outp[i] = hist[i];
}

// ---- reduce slabs; PASS=1 -> rden ; PASS=2 -> c (self loops analytic) ----
template <int PASS>
__global__ __launch_bounds__(256) void k_red(
    const float* __restrict__ slab, const float* __restrict__ a_s,
    const float* __restrict__ a_d, const float* __restrict__ rden_in,
    float* __restrict__ outarr, int N) {
  const int n = blockIdx.x * 256 + threadIdx.x;
  if (n >= N) return;
  const int g = n >> RSHIFT;
  const int i = n & RMASK;
  const float* sp = slab + (size_t)g * T * RSZ + i;
  float sum = 0.f;
#pragma unroll
  for (int t = 0; t < T; ++t) sum += sp[(size_t)t * RSZ];
  float e = a_s[n] + a_d[n];
  e = e > 0.f ? e : 0.2f * e;
  const float ex_self = __expf(e);
  if (PASS == 1)
    outarr[n] = 1.0f / (sum + ex_self + 1e-16f);
  else
    outarr[n] = sum + ex_self * rden_in[n];
}

// ---- px[k] = sum_n c[n]*x[n][k], k<5 (per-block partials) ----
__global__ __launch_bounds__(256) void k_poolx(
    const float* __restrict__ x, const float* __restrict__ c,
    float* __restrict__ partial, int N) {
  float a0 = 0.f, a1 = 0.f, a2 = 0.f, a3 = 0.f, a4 = 0.f;
  for (int n = blockIdx.x * 256 + threadIdx.x; n < N; n += gridDim.x * 256) {
    const float cv = c[n];
    const float* xp = x + (size_t)n * 5;
    a0 += cv * xp[0];
    a1 += cv * xp[1];
    a2 += cv * xp[2];
    a3 += cv * xp[3];
    a4 += cv * xp[4];
  }
#pragma unroll
  for (int o = 32; o > 0; o >>= 1) {
    a0 += __shfl_xor(a0, o, 64);
    a1 += __shfl_xor(a1, o, 64);
    a2 += __shfl_xor(a2, o, 64);
    a3 += __shfl_xor(a3, o, 64);
    a4 += __shfl_xor(a4, o, 64);
  }
  __shared__ float s5[4][5];
  const int lane = threadIdx.x & 63;
  const int w = threadIdx.x >> 6;
  if (lane == 0) {
    s5[w][0] = a0;
    s5[w][1] = a1;
    s5[w][2] = a2;
    s5[w][3] = a3;
    s5[w][4] = a4;
  }
  __syncthreads();
  if (threadIdx.x < 5)
    partial[blockIdx.x * 5 + threadIdx.x] =
        s5[0][threadIdx.x] + s5[1][threadIdx.x] + s5[2][threadIdx.x] +
        s5[3][threadIdx.x];
}

// ---- reduce px partials, pooled = px@W * invN + b_gat, FC 64->72 + relu ----
__global__ __launch_bounds__(256) void k_finish(
    const float* __restrict__ partial, const float* __restrict__ W,
    const float* __restrict__ b_gat, const float* __restrict__ W_fc,
    const float* __restrict__ b_fc, float* __restrict__ out, float invN) {
  __shared__ float pp[POOLX_BLOCKS * 5];
  __shared__ float px[5];
  __shared__ float pooled[64];
  const int t = threadIdx.x;
  if (t < POOLX_BLOCKS * 5) pp[t] = partial[t];
  __syncthreads();
  if (t < 5) {
    float s = 0.f;
    for (int b = 0; b < POOLX_BLOCKS; ++b) s += pp[b * 5 + t];
    px[t] = s * invN;
  }
  __syncthreads();
  if (t < 64) {
    float s = b_gat[t];
#pragma unroll
    for (int k = 0; k < 5; ++k) s += px[k] * W[k * 64 + t];
    pooled[t] = s;
  }
  __syncthreads();
  if (t < 72) {
    float s = b_fc[t];
#pragma unroll
    for (int f = 0; f < 64; ++f) s += pooled[f] * W_fc[f * 72 + t];
    out[t] = s > 0.f ? s : 0.f;
  }
}

extern "C" void kernel_launch(void* const* d_in, const int* in_sizes, int n_in,
                              void* d_out, int out_size, void* d_ws,
                              size_t ws_size, hipStream_t stream) {
  const float* x = (const float*)d_in[0];
  const int* ei = (const int*)d_in[1];
  const float* W = (const float*)d_in[2];
  const float* att_src = (const float*)d_in[3];
  const float* att_dst = (const float*)d_in[4];
  const float* b_gat = (const float*)d_in[5];
  const float* W_fc = (const float*)d_in[6];
  const float* b_fc = (const float*)d_in[7];
  float* out = (float*)d_out;

  const int N = in_sizes[0] / 5;  // 100000
  const int E = in_sizes[1] / 2;  // 1600000

  char* p = (char*)d_ws;
  auto alloc = [&](size_t nbytes) -> void* {
    void* r = (void*)p;
    p += (nbytes + 255) & ~(size_t)255;
    return r;
  };
  float* a_s = (float*)alloc((size_t)N * sizeof(float));
  float* a_d = (float*)alloc((size_t)N * sizeof(float));
  float* rden = (float*)alloc((size_t)N * sizeof(float));
  float* c = (float*)alloc((size_t)N * sizeof(float));
  int* counts_d = (int*)alloc((size_t)NR * BBIN * sizeof(int));
  int* counts_s = (int*)alloc((size_t)NR * BBIN * sizeof(int));
  int* offs_d = (int*)alloc((size_t)NR * BBIN * sizeof(int));
  int* offs_s = (int*)alloc((size_t)NR * BBIN * sizeof(int));
  int* rinfo = (int*)alloc((size_t)4 * NR * sizeof(int));
  uint2* rec_d = (uint2*)alloc((size_t)E * sizeof(uint2));
  uint2* rec_s = (uint2*)alloc((size_t)E * sizeof(uint2));
  float* slab = (float*)alloc((size_t)NR * T * RSZ * sizeof(float));  // 3.3MB
  float* partial = (float*)alloc((size_t)POOLX_BLOCKS * 5 * sizeof(float));

  k_att<<<(N + 3) / 4, 256, 0, stream>>>(x, W, att_src, att_dst, a_s, a_d, N);
  k_count<<<BBIN, BINTHR, 0, stream>>>(ei, counts_d, counts_s, E);
  k_scan<<<1, BINTHR, 0, stream>>>(counts_d, counts_s, offs_d, offs_s, rinfo);
  k_scatter<<<BBIN, BINTHR, 0, stream>>>(ei, a_s, a_d, offs_d, offs_s, rec_d,
                                         rec_s, E);
  k_hist<1><<<NR * T, 256, 0, stream>>>(rec_d, rinfo, nullptr, slab);
  k_red<1><<<(N + 255) / 256, 256, 0, stream>>>(slab, a_s, a_d, nullptr, rden,
                                                N);
  k_hist<2><<<NR * T, 256, 0, stream>>>(rec_s, rinfo, rden, slab);
  k_red<2><<<(N + 255) / 256, 256, 0, stream>>>(slab, a_s, a_d, rden, c, N);
  k_poolx<<<POOLX_BLOCKS, 256, 0, stream>>>(x, c, partial, N);
  k_finish<<<1, 256, 0, stream>>>(partial, W, b_gat, W_fc, b_fc, out,
                                  1.0f / (float)N);
}